// Round 1
// baseline (60.565 us; speedup 1.0000x reference)
//
#include <hip/hip_runtime.h>
#include <math.h>

// Problem constants (fixed by the reference):
//   B=8, N=256, D=16, K+1=4, REL=6, OUT=3
// Closed form (A = J - I fully connected, As input is IGNORED):
//   d<REL : Zagg = {0, T1-256*x1, 256*x2-T2-255*x1, 256*T3-65536*x3-255*x1}
//   d>=REL: Zagg = {x0, T1-x1, 254*T2+x2, 64771*T3-x3}
//   actions[b,i,o] = sum_{d,k} Zagg[d,k] * W[(d*4+k)*3+o], NaN->0
// where x_k = Xs[b,i,d,k], T_k[d] = sum_i Xs[b,i,d,k].

constexpr int NN   = 256;
constexpr int DD   = 16;
constexpr int KP1  = 4;
constexpr int RELC = 6;
constexpr int LDS4 = 17;   // padded row stride in float4 units (16 data + 1 pad)

__global__ __launch_bounds__(256)
void reynolds_kernel(const float* __restrict__ Xs,
                     const float* __restrict__ W,
                     float* __restrict__ out) {
    __shared__ float4 sX[NN * LDS4];   // 256*17*16B = 68 KiB, padded rows
    __shared__ float4 sPS[256];        // per-thread partial channel sums
    __shared__ float  sT[DD * KP1];    // T[d*4+k]
    __shared__ float  sW[DD * KP1 * 3];

    const int b = blockIdx.x;
    const int t = threadIdx.x;

    // --- Stage batch slice (256 rows x 16 float4) into LDS, coalesced, and
    //     accumulate per-thread partial sums. Thread t always loads float4
    //     column c = t&15 (since 256*i is a multiple of 16), i.e. a fixed
    //     (d=c, k=0..3) channel quad over rows {t>>4 + 16*i}.
    const float4* src = (const float4*)(Xs + (size_t)b * NN * DD * KP1);
    const int c = t & 15;
    float4 acc4 = make_float4(0.f, 0.f, 0.f, 0.f);
#pragma unroll
    for (int i = 0; i < 16; ++i) {
        const int g = t + i * 256;         // global float4 index in slice
        const float4 v = src[g];
        sX[(g >> 4) * LDS4 + c] = v;
        acc4.x += v.x; acc4.y += v.y; acc4.z += v.z; acc4.w += v.w;
    }
    sPS[t] = acc4;
    if (t < DD * KP1 * 3) sW[t] = W[t];
    __syncthreads();

    // --- Reduce partials to T[d*4+k]: thread t<64 sums the 16 partials that
    //     carry its (d,k). Word index = t + 64*j -> consecutive, conflict-free.
    if (t < 64) {
        const int d = t >> 2, k = t & 3;
        float s = 0.f;
#pragma unroll
        for (int j = 0; j < 16; ++j) {
            const float* p = (const float*)&sPS[d + 16 * j];
            s += p[k];
        }
        sT[t] = s;
    }
    __syncthreads();

    // --- Per-row closed-form evaluation.
    const float* xr = (const float*)&sX[t * LDS4];
    float acc0 = 0.f, acc1 = 0.f, acc2 = 0.f;
#pragma unroll
    for (int d = 0; d < DD; ++d) {
        const float x0 = xr[d * 4 + 0];
        const float x1 = xr[d * 4 + 1];
        const float x2 = xr[d * 4 + 2];
        const float x3 = xr[d * 4 + 3];
        const float T1 = sT[d * 4 + 1];
        const float T2 = sT[d * 4 + 2];
        const float T3 = sT[d * 4 + 3];
        float z0, z1, z2, z3;
        if (d < RELC) {   // compile-time branch (loop fully unrolled)
            z0 = 0.f;
            z1 = T1 - 256.f * x1;
            z2 = 256.f * x2 - T2 - 255.f * x1;
            z3 = 256.f * T3 - 65536.f * x3 - 255.f * x1;
        } else {
            z0 = x0;
            z1 = T1 - x1;
            z2 = 254.f * T2 + x2;
            z3 = 64771.f * T3 - x3;
        }
        const float* w = &sW[d * 12];
        acc0 += z0 * w[0] + z1 * w[3] + z2 * w[6] + z3 * w[9];
        acc1 += z0 * w[1] + z1 * w[4] + z2 * w[7] + z3 * w[10];
        acc2 += z0 * w[2] + z1 * w[5] + z2 * w[8] + z3 * w[11];
    }

    const size_t o = ((size_t)b * NN + t) * 3;
    out[o + 0] = isnan(acc0) ? 0.f : acc0;
    out[o + 1] = isnan(acc1) ? 0.f : acc1;
    out[o + 2] = isnan(acc2) ? 0.f : acc2;
}

extern "C" void kernel_launch(void* const* d_in, const int* in_sizes, int n_in,
                              void* d_out, int out_size, void* d_ws, size_t ws_size,
                              hipStream_t stream) {
    // d_in[0] = As (IGNORED by the reference forward), d_in[1] = Xs, d_in[2] = W
    const float* Xs = (const float*)d_in[1];
    const float* W  = (const float*)d_in[2];
    float* out = (float*)d_out;
    reynolds_kernel<<<dim3(8), dim3(256), 0, stream>>>(Xs, W, out);
}